// Round 1
// baseline (120.768 us; speedup 1.0000x reference)
//
#include <hip/hip_runtime.h>
#include <hip/hip_bf16.h>
#include <hip/hip_cooperative_groups.h>

namespace cg = cooperative_groups;

// Problem constants (JointAnfisNet)
#define BATCH      16384
#define N_IN       6
#define N_MF       5
#define N_FUZZ     30      // N_IN * N_MF
#define N_RULES    2048
#define N_OUT_MEM  12

// Decomposition (unchanged from 80.6us version):
//   256 rows/block, 4 rows per lane packed as f16x4 (uint2) -> one ds_read_b64
//   serves 4 rows. Rules split 4 ways across blocks so grid stays 256 = 64 row
//   groups x 4 rule splits (fills all 256 CUs).
// NEW this round: single cooperative kernel. prep is folded into the rule loop
//   as wave-uniform SCALAR loads (s_load of input_rules/output_rules/out_centers
//   -- scalar pipe runs parallel to the DS-bound gather loop, so it is free,
//   unlike LDS-broadcast reads which would cost ~2 extra DS issue slots/rule).
//   finalize is folded behind grid.sync(). Dispatches: 3 -> 1.
#define ROWS_PB    256
#define SPLITS     4
#define RULES_PB   (N_RULES / SPLITS)     // 512
#define THREADS    1024
#define WAVES      16
#define RULES_PW   (RULES_PB / WAVES)     // 32
#define ROWGROUPS  (BATCH / ROWS_PB)      // 64
#define FIN_ROWS   (BATCH / (ROWGROUPS * SPLITS))   // 64 rows finalized per block

// d_ws layout (fallback path still uses packed/ow; fused path only partials)
#define WS_PACKED_OFF  0                       // u32[2048]    = 8 KB
#define WS_OW_OFF      8192                    // float2[2048] = 16 KB
#define WS_PART_OFF    24576                   // f32[SPLITS*3*BATCH] = 768 KB

typedef _Float16 f16x2 __attribute__((ext_vector_type(2)));

// ---------------------------------------------------------------------------
// Deterministic dtype probe: mf_scales is genuinely in [0.5, 1.5]. Interpret
// its first 60 bytes as 30 bf16 halves; all-in-[0.4,1.6] => bf16 data.
// ---------------------------------------------------------------------------
__device__ inline int probe_is_bf16(const void* mfs) {
    const unsigned int* w = (const unsigned int*)mfs;
    int ok = 1;
    for (int k = 0; k < 15; ++k) {
        const unsigned int v = w[k];
        const float lo = __uint_as_float(v << 16);
        const float hi = __uint_as_float(v & 0xffff0000u);
        if (!(lo >= 0.4f && lo <= 1.6f && hi >= 0.4f && hi <= 1.6f)) { ok = 0; break; }
    }
    return ok;
}

// ---------------------------------------------------------------------------
// Fused single-dispatch kernel (cooperative). Phases:
//   stage x + MF params -> fuzzify -> rule loop (inline scalar rule fetch)
//   -> block reduce -> partials -> grid.sync() -> finalize 64 rows/block.
// ---------------------------------------------------------------------------
__global__ __launch_bounds__(THREADS, 4)
void anfis_fused(const void* __restrict__ x_,
                 const void* __restrict__ mfc_,
                 const void* __restrict__ mfs_,
                 const void* __restrict__ oc_,
                 const int* __restrict__ input_rules,
                 const int* __restrict__ output_rules,
                 float* __restrict__ partials,
                 void* __restrict__ out_) {
    __shared__ float xs[ROWS_PB * N_IN];       // 6 KB staged x
    __shared__ float2 cinv[N_FUZZ];            // (center, 1/scale)
    __shared__ uint2 fuzz4[N_FUZZ][64];        // 15 KB, 4 rows/lane as f16x4
    __shared__ float pl1[WAVES][ROWS_PB];      // 16 KB
    __shared__ float pd0[WAVES][ROWS_PB];      // 16 KB
    __shared__ float pd1[WAVES][ROWS_PB];      // 16 KB
    __shared__ int flag;

    const int t     = threadIdx.x;
    const int g     = blockIdx.x >> 2;         // row group 0..63
    const int split = blockIdx.x & 3;          // rule split 0..3
    const int row0  = g * ROWS_PB;

    if (t == 0) flag = probe_is_bf16(mfs_);
    __syncthreads();
    const int is_bf16 = __builtin_amdgcn_readfirstlane(flag);

    // ---- stage x rows + MF params into LDS ----
    if (is_bf16) {
        const unsigned short* xp = (const unsigned short*)x_ + row0 * N_IN;
        for (int i = t; i < ROWS_PB * N_IN; i += THREADS)
            xs[i] = __uint_as_float((unsigned int)xp[i] << 16);
    } else {
        const float* xp = (const float*)x_ + row0 * N_IN;
        for (int i = t; i < ROWS_PB * N_IN; i += THREADS) xs[i] = xp[i];
    }
    if (t < N_FUZZ) {
        float c, s;
        if (is_bf16) {
            c = __uint_as_float((unsigned int)((const unsigned short*)mfc_)[t] << 16);
            s = __uint_as_float((unsigned int)((const unsigned short*)mfs_)[t] << 16);
        } else {
            c = ((const float*)mfc_)[t];
            s = ((const float*)mfs_)[t];
        }
        cinv[t] = make_float2(c, 1.0f / s);
    }
    __syncthreads();

    // ---- fuzzify: 30 x 64 uint2 entries, each = 4 rows' exp(-z^2) as f16 ----
    for (int e = t; e < N_FUZZ * 64; e += THREADS) {
        const int v    = e >> 6;    // MF value index 0..29
        const int lane = e & 63;
        const int i    = v / N_MF;  // input index
        const float2 ci = cinv[v];
        float f[4];
#pragma unroll
        for (int k = 0; k < 4; ++k) {
            const float z = (xs[(lane + 64 * k) * N_IN + i] - ci.x) * ci.y;
            f[k] = __expf(-z * z);
        }
        f16x2 a = { (_Float16)f[0], (_Float16)f[1] };   // rows lane, lane+64
        f16x2 b = { (_Float16)f[2], (_Float16)f[3] };   // rows lane+128, +192
        uint2 u;
        u.x = __builtin_bit_cast(unsigned int, a);
        u.y = __builtin_bit_cast(unsigned int, b);
        fuzz4[v][lane] = u;
    }
    __syncthreads();

    // ---- rule loop: wave-uniform r -> scalar rule fetch, 6 b64 gathers ----
    const int lane = t & 63;
    const int wave = __builtin_amdgcn_readfirstlane(t >> 6);
    const uint2* fz = &fuzz4[0][0];
    const char* ocb = (const char*)oc_;
    const unsigned sh = is_bf16 ? 1u : 2u;     // byte shift into out_centers

    float l1[4] = {0.f, 0.f, 0.f, 0.f};
    float d0[4] = {0.f, 0.f, 0.f, 0.f};
    float d1[4] = {0.f, 0.f, 0.f, 0.f};

    const int rbase = split * RULES_PB + wave * RULES_PW;
#pragma unroll 4
    for (int j = 0; j < RULES_PW; ++j) {
        const int r = rbase + j;
        // 6 MF indices, wave-uniform -> s_load (values are already in [0,30))
        const int* rp = input_rules + r * N_IN;
        const int i0 = rp[0], i1 = rp[1], i2 = rp[2];
        const int i3 = rp[3], i4 = rp[4], i5 = rp[5];
        // out-center gather, wave-uniform + branchless dword access -> scalar
        const int o0i = output_rules[2 * r + 0];
        const int o1i = output_rules[2 * r + 1];
        const unsigned b0 = ((unsigned)o0i) << sh;
        const unsigned b1 = ((unsigned)o1i) << sh;
        const unsigned w0_ = *(const unsigned*)(ocb + (b0 & ~3u));
        const unsigned w1_ = *(const unsigned*)(ocb + (b1 & ~3u));
        const unsigned v0 = is_bf16 ? ((b0 & 2u) ? (w0_ & 0xffff0000u) : (w0_ << 16)) : w0_;
        const unsigned v1 = is_bf16 ? ((b1 & 2u) ? (w1_ & 0xffff0000u) : (w1_ << 16)) : w1_;
        const float ox = __uint_as_float(v0);
        const float oy = __uint_as_float(v1);

        const uint2 g0 = fz[i0 * 64 + lane];
        const uint2 g1 = fz[i1 * 64 + lane];
        const uint2 g2 = fz[i2 * 64 + lane];
        const uint2 g3 = fz[i3 * 64 + lane];
        const uint2 g4 = fz[i4 * 64 + lane];
        const uint2 g5 = fz[i5 * 64 + lane];
        f16x2 wa = __builtin_elementwise_min(__builtin_bit_cast(f16x2, g0.x),
                                             __builtin_bit_cast(f16x2, g1.x));
        wa = __builtin_elementwise_min(wa, __builtin_bit_cast(f16x2, g2.x));
        wa = __builtin_elementwise_min(wa, __builtin_bit_cast(f16x2, g3.x));
        wa = __builtin_elementwise_min(wa, __builtin_bit_cast(f16x2, g4.x));
        wa = __builtin_elementwise_min(wa, __builtin_bit_cast(f16x2, g5.x));
        f16x2 wb = __builtin_elementwise_min(__builtin_bit_cast(f16x2, g0.y),
                                             __builtin_bit_cast(f16x2, g1.y));
        wb = __builtin_elementwise_min(wb, __builtin_bit_cast(f16x2, g2.y));
        wb = __builtin_elementwise_min(wb, __builtin_bit_cast(f16x2, g3.y));
        wb = __builtin_elementwise_min(wb, __builtin_bit_cast(f16x2, g4.y));
        wb = __builtin_elementwise_min(wb, __builtin_bit_cast(f16x2, g5.y));
        const float w0 = (float)wa.x, w1 = (float)wa.y;
        const float w2 = (float)wb.x, w3 = (float)wb.y;
        l1[0] += w0; d0[0] += w0 * ox; d1[0] += w0 * oy;
        l1[1] += w1; d0[1] += w1 * ox; d1[1] += w1 * oy;
        l1[2] += w2; d0[2] += w2 * ox; d1[2] += w2 * oy;
        l1[3] += w3; d0[3] += w3 * ox; d1[3] += w3 * oy;
    }
#pragma unroll
    for (int k = 0; k < 4; ++k) {
        pl1[wave][lane + 64 * k] = l1[k];
        pd0[wave][lane + 64 * k] = d0[k];
        pd1[wave][lane + 64 * k] = d1[k];
    }
    __syncthreads();

    // ---- block reduction over 16 waves; write split partials ----
    if (t < ROWS_PB) {
        float a = 0.f, b = 0.f, c = 0.f;
#pragma unroll
        for (int wv = 0; wv < WAVES; ++wv) {
            a += pl1[wv][t];
            b += pd0[wv][t];
            c += pd1[wv][t];
        }
        const int row = row0 + t;
        partials[(split * 3 + 0) * BATCH + row] = a;
        partials[(split * 3 + 1) * BATCH + row] = b;
        partials[(split * 3 + 2) * BATCH + row] = c;
    }

    // ---- grid-wide sync, then finalize 64 rows per block ----
    cg::this_grid().sync();

    if (t < FIN_ROWS) {
        const int row = blockIdx.x * FIN_ROWS + t;
        float a = 0.f, b = 0.f, c = 0.f;
#pragma unroll
        for (int s = 0; s < SPLITS; ++s) {
            a += partials[(s * 3 + 0) * BATCH + row];
            b += partials[(s * 3 + 1) * BATCH + row];
            c += partials[(s * 3 + 2) * BATCH + row];
        }
        const float inv = 1.0f / fmaxf(a, 1e-12f);
        const float y0 = tanhf(b * inv) * 4.00f + 0.00f;
        const float y1 = tanhf(c * inv) * 0.75f + 0.75f;
        if (is_bf16) {
            __hip_bfloat162 o;
            o.x = __float2bfloat16(y0);
            o.y = __float2bfloat16(y1);
            ((__hip_bfloat162*)out_)[row] = o;
        } else {
            ((float2*)out_)[row] = make_float2(y0, y1);
        }
    }
}

// ===========================================================================
// Fallback path (3 dispatches) -- used only if cooperative launch is rejected
// by graph capture. Identical to the verified 80.6us version.
// ===========================================================================
__global__ void anfis_prep(const int* __restrict__ input_rules,
                           const int* __restrict__ output_rules,
                           const void* __restrict__ oc_,
                           const void* __restrict__ mfs_,
                           unsigned int* __restrict__ packed,
                           float2* __restrict__ ow) {
    __shared__ int flag;
    if (threadIdx.x == 0) flag = probe_is_bf16(mfs_);
    __syncthreads();
    const bool is_bf16 = (flag != 0);

    const int r = blockIdx.x * blockDim.x + threadIdx.x;
    if (r >= N_RULES) return;
    const int* rp = input_rules + r * N_IN;
    unsigned int p = 0;
#pragma unroll
    for (int i = 0; i < N_IN; ++i) p |= ((unsigned int)rp[i] & 31u) << (5 * i);
    packed[r] = p;

    const int o0i = output_rules[2 * r + 0];
    const int o1i = output_rules[2 * r + 1];
    float o0, o1;
    if (is_bf16) {
        const unsigned short* oc = (const unsigned short*)oc_;
        o0 = __uint_as_float((unsigned int)oc[o0i] << 16);
        o1 = __uint_as_float((unsigned int)oc[o1i] << 16);
    } else {
        const float* oc = (const float*)oc_;
        o0 = oc[o0i]; o1 = oc[o1i];
    }
    ow[r] = make_float2(o0, o1);
}

__global__ __launch_bounds__(THREADS, 4)
void anfis_main(const void* __restrict__ x_,
                const void* __restrict__ mfc_,
                const void* __restrict__ mfs_,
                const unsigned int* __restrict__ packed,
                const float2* __restrict__ ow,
                float* __restrict__ partials) {
    __shared__ float xs[ROWS_PB * N_IN];
    __shared__ float2 cinv[N_FUZZ];
    __shared__ uint2 fuzz4[N_FUZZ][64];
    __shared__ float pl1[WAVES][ROWS_PB];
    __shared__ float pd0[WAVES][ROWS_PB];
    __shared__ float pd1[WAVES][ROWS_PB];
    __shared__ int flag;

    const int t     = threadIdx.x;
    const int g     = blockIdx.x >> 2;
    const int split = blockIdx.x & 3;
    const int row0  = g * ROWS_PB;

    if (t == 0) flag = probe_is_bf16(mfs_);
    __syncthreads();
    const bool is_bf16 = (flag != 0);

    if (is_bf16) {
        const unsigned short* xp = (const unsigned short*)x_ + row0 * N_IN;
        for (int i = t; i < ROWS_PB * N_IN; i += THREADS)
            xs[i] = __uint_as_float((unsigned int)xp[i] << 16);
    } else {
        const float* xp = (const float*)x_ + row0 * N_IN;
        for (int i = t; i < ROWS_PB * N_IN; i += THREADS) xs[i] = xp[i];
    }
    if (t < N_FUZZ) {
        float c, s;
        if (is_bf16) {
            c = __uint_as_float((unsigned int)((const unsigned short*)mfc_)[t] << 16);
            s = __uint_as_float((unsigned int)((const unsigned short*)mfs_)[t] << 16);
        } else {
            c = ((const float*)mfc_)[t];
            s = ((const float*)mfs_)[t];
        }
        cinv[t] = make_float2(c, 1.0f / s);
    }
    __syncthreads();

    for (int e = t; e < N_FUZZ * 64; e += THREADS) {
        const int v    = e >> 6;
        const int lane = e & 63;
        const int i    = v / N_MF;
        const float2 ci = cinv[v];
        float f[4];
#pragma unroll
        for (int k = 0; k < 4; ++k) {
            const float z = (xs[(lane + 64 * k) * N_IN + i] - ci.x) * ci.y;
            f[k] = __expf(-z * z);
        }
        f16x2 a = { (_Float16)f[0], (_Float16)f[1] };
        f16x2 b = { (_Float16)f[2], (_Float16)f[3] };
        uint2 u;
        u.x = __builtin_bit_cast(unsigned int, a);
        u.y = __builtin_bit_cast(unsigned int, b);
        fuzz4[v][lane] = u;
    }
    __syncthreads();

    const int lane = t & 63;
    const int wave = __builtin_amdgcn_readfirstlane(t >> 6);
    const uint2* fz = &fuzz4[0][0];

    float l1[4] = {0.f, 0.f, 0.f, 0.f};
    float d0[4] = {0.f, 0.f, 0.f, 0.f};
    float d1[4] = {0.f, 0.f, 0.f, 0.f};

    const int rbase = split * RULES_PB + wave * RULES_PW;
#pragma unroll 4
    for (int j = 0; j < RULES_PW; ++j) {
        const int r = rbase + j;
        const unsigned int p = packed[r];
        const float2 o = ow[r];
        const uint2 g0 = fz[((p      ) & 31u) * 64 + lane];
        const uint2 g1 = fz[((p >> 5 ) & 31u) * 64 + lane];
        const uint2 g2 = fz[((p >> 10) & 31u) * 64 + lane];
        const uint2 g3 = fz[((p >> 15) & 31u) * 64 + lane];
        const uint2 g4 = fz[((p >> 20) & 31u) * 64 + lane];
        const uint2 g5 = fz[((p >> 25) & 31u) * 64 + lane];
        f16x2 wa = __builtin_elementwise_min(__builtin_bit_cast(f16x2, g0.x),
                                             __builtin_bit_cast(f16x2, g1.x));
        wa = __builtin_elementwise_min(wa, __builtin_bit_cast(f16x2, g2.x));
        wa = __builtin_elementwise_min(wa, __builtin_bit_cast(f16x2, g3.x));
        wa = __builtin_elementwise_min(wa, __builtin_bit_cast(f16x2, g4.x));
        wa = __builtin_elementwise_min(wa, __builtin_bit_cast(f16x2, g5.x));
        f16x2 wb = __builtin_elementwise_min(__builtin_bit_cast(f16x2, g0.y),
                                             __builtin_bit_cast(f16x2, g1.y));
        wb = __builtin_elementwise_min(wb, __builtin_bit_cast(f16x2, g2.y));
        wb = __builtin_elementwise_min(wb, __builtin_bit_cast(f16x2, g3.y));
        wb = __builtin_elementwise_min(wb, __builtin_bit_cast(f16x2, g4.y));
        wb = __builtin_elementwise_min(wb, __builtin_bit_cast(f16x2, g5.y));
        const float w0 = (float)wa.x, w1 = (float)wa.y;
        const float w2 = (float)wb.x, w3 = (float)wb.y;
        l1[0] += w0; d0[0] += w0 * o.x; d1[0] += w0 * o.y;
        l1[1] += w1; d0[1] += w1 * o.x; d1[1] += w1 * o.y;
        l1[2] += w2; d0[2] += w2 * o.x; d1[2] += w2 * o.y;
        l1[3] += w3; d0[3] += w3 * o.x; d1[3] += w3 * o.y;
    }
#pragma unroll
    for (int k = 0; k < 4; ++k) {
        pl1[wave][lane + 64 * k] = l1[k];
        pd0[wave][lane + 64 * k] = d0[k];
        pd1[wave][lane + 64 * k] = d1[k];
    }
    __syncthreads();

    if (t < ROWS_PB) {
        float a = 0.f, b = 0.f, c = 0.f;
#pragma unroll
        for (int wv = 0; wv < WAVES; ++wv) {
            a += pl1[wv][t];
            b += pd0[wv][t];
            c += pd1[wv][t];
        }
        const int row = row0 + t;
        partials[(split * 3 + 0) * BATCH + row] = a;
        partials[(split * 3 + 1) * BATCH + row] = b;
        partials[(split * 3 + 2) * BATCH + row] = c;
    }
}

__global__ void anfis_finalize(const float* __restrict__ partials,
                               const void* __restrict__ mfs_,
                               void* __restrict__ out_) {
    __shared__ int flag;
    if (threadIdx.x == 0) flag = probe_is_bf16(mfs_);
    __syncthreads();
    const int row = blockIdx.x * blockDim.x + threadIdx.x;
    if (row >= BATCH) return;
    float l1 = 0.f, d0 = 0.f, d1 = 0.f;
#pragma unroll
    for (int s = 0; s < SPLITS; ++s) {
        l1 += partials[(s * 3 + 0) * BATCH + row];
        d0 += partials[(s * 3 + 1) * BATCH + row];
        d1 += partials[(s * 3 + 2) * BATCH + row];
    }
    const float inv = 1.0f / fmaxf(l1, 1e-12f);
    const float y0 = tanhf(d0 * inv) * 4.00f + 0.00f;
    const float y1 = tanhf(d1 * inv) * 0.75f + 0.75f;
    if (flag) {
        __hip_bfloat162 o;
        o.x = __float2bfloat16(y0);
        o.y = __float2bfloat16(y1);
        ((__hip_bfloat162*)out_)[row] = o;
    } else {
        ((float2*)out_)[row] = make_float2(y0, y1);
    }
}

extern "C" void kernel_launch(void* const* d_in, const int* in_sizes, int n_in,
                              void* d_out, int out_size, void* d_ws, size_t ws_size,
                              hipStream_t stream) {
    (void)in_sizes; (void)n_in; (void)out_size; (void)ws_size;
    const void* x_   = d_in[0];
    const void* mfc_ = d_in[1];
    const void* mfs_ = d_in[2];
    const void* oc_  = d_in[3];
    const int* input_rules  = (const int*)d_in[4];
    const int* output_rules = (const int*)d_in[5];

    float* parts = (float*)((char*)d_ws + WS_PART_OFF);
    void*  out_  = d_out;

    void* args[] = { (void*)&x_, (void*)&mfc_, (void*)&mfs_, (void*)&oc_,
                     (void*)&input_rules, (void*)&output_rules,
                     (void*)&parts, (void*)&out_ };
    hipError_t err = hipLaunchCooperativeKernel(
        (const void*)anfis_fused, dim3(ROWGROUPS * SPLITS), dim3(THREADS),
        args, 0, stream);

    if (err != hipSuccess) {
        // Fallback: verified 3-dispatch path
        unsigned int* packed = (unsigned int*)((char*)d_ws + WS_PACKED_OFF);
        float2*       ow     = (float2*)((char*)d_ws + WS_OW_OFF);
        anfis_prep<<<(N_RULES + 255) / 256, 256, 0, stream>>>(
            input_rules, output_rules, oc_, mfs_, packed, ow);
        anfis_main<<<ROWGROUPS * SPLITS, THREADS, 0, stream>>>(
            x_, mfc_, mfs_, packed, ow, parts);
        anfis_finalize<<<BATCH / 256, 256, 0, stream>>>(parts, mfs_, d_out);
    }
}